// Round 1
// baseline (184.985 us; speedup 1.0000x reference)
//
#include <hip/hip_runtime.h>
#include <hip/hip_bf16.h>
#include <math.h>

// Problem constants
#define BB 2
#define SS 2048
#define DD 512
#define MTOT 4096   // B*S
#define WINW 64

typedef __attribute__((ext_vector_type(8))) short sv8;   // 8 bf16
typedef __attribute__((ext_vector_type(4))) float f32x4;

// workspace layout (bytes)
static const size_t OFF_XB   = 0;               // bf16 x      [4096][512]   4 MB
static const size_t OFF_WT   = 4194304;         // bf16 Wt     [5][512][512] 2.5 MB (q,k,v,r,o; [n][k])
static const size_t OFF_BIAS = 6815744;         // f32 bias    [2048]        8 KB (bq|bk|bv|br)
static const size_t OFF_Y    = 6823936;         // bf16 Y      [4096][2048]  16 MB (q|k|v|sence)
static const size_t OFF_ATT  = 23601152;        // bf16 att    [4096][512]   4 MB
static const size_t OFF_READ = 27795456;        // f32 read    [4096][512]   8 MB

static __device__ __forceinline__ float bf2f(short s) {
    unsigned u = ((unsigned)(unsigned short)s) << 16;
    return __builtin_bit_cast(float, u);
}
static __device__ __forceinline__ short f2bf(float f) {
    unsigned u = __builtin_bit_cast(unsigned, f);
    unsigned r = 0x7fffu + ((u >> 16) & 1u);
    u += r;
    return (short)(u >> 16);
}

// ---------------- cast x to bf16 ----------------
__global__ __launch_bounds__(256) void cast_x(const float* __restrict__ x,
                                              short* __restrict__ xb, int n4) {
    int i = blockIdx.x * 256 + threadIdx.x;
    if (i < n4) {
        float4 v = ((const float4*)x)[i];
        short4 o;
        o.x = f2bf(v.x); o.y = f2bf(v.y); o.z = f2bf(v.z); o.w = f2bf(v.w);
        ((short4*)xb)[i] = o;
    }
}

// ------------- cast + transpose weights -> Wt[z][n][k] bf16 -------------
__global__ __launch_bounds__(256) void cast_w(const float* __restrict__ Wq,
                                              const float* __restrict__ Wk,
                                              const float* __restrict__ Wv,
                                              const float* __restrict__ Wr,
                                              const float* __restrict__ Wo,
                                              short* __restrict__ wt) {
    __shared__ float tile[32][33];
    int z = blockIdx.z;
    const float* W = (z == 0) ? Wq : (z == 1) ? Wk : (z == 2) ? Wv : (z == 3) ? Wr : Wo;
    int k0 = blockIdx.y * 32, n0 = blockIdx.x * 32;
    int tx = threadIdx.x & 31, ty = threadIdx.x >> 5;  // ty in 0..7
    for (int r = ty; r < 32; r += 8)
        tile[r][tx] = W[(size_t)(k0 + r) * 512 + n0 + tx];
    __syncthreads();
    short* o = wt + (size_t)z * 512 * 512;
    for (int r = ty; r < 32; r += 8)
        o[(size_t)(n0 + r) * 512 + k0 + tx] = f2bf(tile[tx][r]);
}

// ------------- concat biases -------------
__global__ __launch_bounds__(256) void prep_bias(const float* __restrict__ bq,
                                                 const float* __restrict__ bk,
                                                 const float* __restrict__ bv,
                                                 const float* __restrict__ br,
                                                 float* __restrict__ ball) {
    int i = blockIdx.x * 256 + threadIdx.x;  // 0..2047
    int sel = i >> 9;
    const float* src = (sel == 0) ? bq : (sel == 1) ? bk : (sel == 2) ? bv : br;
    ball[i] = src[i & 511];
}

// ------------- bf16 MFMA GEMM: C[m][n] = A[m][:] . Bt[n][:] + bias[n] -------------
// A: [M][512] bf16, Bt: [N][512] bf16 (row n = output col n), 128x128 tile, BK=64
template <int OUT_F32>
__global__ __launch_bounds__(256) void gemm_bt(const short* __restrict__ A,
                                               const short* __restrict__ Bt,
                                               const float* __restrict__ bias,
                                               void* __restrict__ Cout, int ldc) {
    const int K = 512;
    const int LDL = 72;  // 64 + 8 pad (keeps 16B alignment, breaks bank stride)
    __shared__ __align__(16) short lA[128 * LDL];
    __shared__ __align__(16) short lB[128 * LDL];
    int tid = threadIdx.x;
    int mbase = blockIdx.y * 128;
    int nbase = blockIdx.x * 128;
    int lane = tid & 63, wave = tid >> 6;
    int wm = wave >> 1, wn = wave & 1;

    f32x4 acc[4][4] = {};

    for (int k0 = 0; k0 < K; k0 += 64) {
#pragma unroll
        for (int t = 0; t < 4; ++t) {
            int c = tid + t * 256;           // 0..1023
            int row = c >> 3, slot = c & 7;  // 128 rows x 8 x 16B
            sv8 va = *(const sv8*)(A + (size_t)(mbase + row) * K + k0 + slot * 8);
            *(sv8*)&lA[row * LDL + slot * 8] = va;
            sv8 vb = *(const sv8*)(Bt + (size_t)(nbase + row) * K + k0 + slot * 8);
            *(sv8*)&lB[row * LDL + slot * 8] = vb;
        }
        __syncthreads();
#pragma unroll
        for (int kk = 0; kk < 2; ++kk) {
            int koff = kk * 32 + (lane >> 4) * 8;
            sv8 af[4], bfr[4];
#pragma unroll
            for (int m = 0; m < 4; ++m)
                af[m] = *(const sv8*)&lA[(wm * 64 + m * 16 + (lane & 15)) * LDL + koff];
#pragma unroll
            for (int n = 0; n < 4; ++n)
                bfr[n] = *(const sv8*)&lB[(wn * 64 + n * 16 + (lane & 15)) * LDL + koff];
#pragma unroll
            for (int m = 0; m < 4; ++m)
#pragma unroll
                for (int n = 0; n < 4; ++n)
                    acc[m][n] = __builtin_amdgcn_mfma_f32_16x16x32_bf16(
                        af[m], bfr[n], acc[m][n], 0, 0, 0);
        }
        __syncthreads();
    }

    // epilogue: D[row=(lane>>4)*4+j][col=lane&15] per 16x16 fragment
    int r0 = (lane >> 4) * 4, c0 = lane & 15;
#pragma unroll
    for (int m = 0; m < 4; ++m) {
#pragma unroll
        for (int n = 0; n < 4; ++n) {
            int col = nbase + wn * 64 + n * 16 + c0;
            float bv = bias[col];
#pragma unroll
            for (int j = 0; j < 4; ++j) {
                int row = mbase + wm * 64 + m * 16 + r0 + j;
                float v = acc[m][n][j] + bv;
                if (OUT_F32)
                    ((float*)Cout)[(size_t)row * ldc + col] = v;
                else
                    ((short*)Cout)[(size_t)row * ldc + col] = f2bf(v);
            }
        }
    }
}

// ------------- local attention: one wave per query row -------------
// Y: [4096][2048] bf16 = [q|k|v|sence]; att: [4096][512] bf16
__global__ __launch_bounds__(256) void attn_kernel(const short* __restrict__ Y,
                                                   short* __restrict__ att) {
    int wave = threadIdx.x >> 6, lane = threadIdx.x & 63;
    int s = blockIdx.x * 4 + wave;  // 0..4095
    int b = s >> 11, t = s & 2047;
    const short* q = Y + (size_t)s * 2048;
    const short* Kbase = Y + ((size_t)(b << 11)) * 2048 + 512;
    const short* Vbase = Y + ((size_t)(b << 11)) * 2048 + 1024;

    // QK phase: lane w owns key j = t-63+w
    int jlane = t - 63 + lane;
    float score = -1e30f;
    if (jlane >= 0) {
        const short* krow = Kbase + (size_t)jlane * 2048;
        float acc = 0.f;
        for (int c = 0; c < 64; ++c) {
            sv8 qv = *(const sv8*)(q + c * 8);
            sv8 kv = *(const sv8*)(krow + c * 8);
#pragma unroll
            for (int e = 0; e < 8; ++e) acc += bf2f(qv[e]) * bf2f(kv[e]);
        }
        score = acc * 0.04419417382415922f;  // 1/sqrt(512)
    }
    // softmax across 64 lanes
    float m = score;
#pragma unroll
    for (int off = 32; off; off >>= 1) m = fmaxf(m, __shfl_xor(m, off));
    float p = (jlane >= 0) ? __expf(score - m) : 0.f;
    float sum = p;
#pragma unroll
    for (int off = 32; off; off >>= 1) sum += __shfl_xor(sum, off);
    p /= sum;

    // PV phase: lane owns dims [lane*8, lane*8+8)
    float o[8] = {0.f, 0.f, 0.f, 0.f, 0.f, 0.f, 0.f, 0.f};
    int w0 = (t >= 63) ? 0 : (63 - t);
    for (int w = w0; w < 64; ++w) {
        float pw = __shfl(p, w);
        const short* vrow = Vbase + (size_t)(t - 63 + w) * 2048;
        sv8 vv = *(const sv8*)(vrow + lane * 8);
#pragma unroll
        for (int e = 0; e < 8; ++e) o[e] += pw * bf2f(vv[e]);
    }
    sv8 ov;
#pragma unroll
    for (int e = 0; e < 8; ++e) ov[e] = f2bf(o[e]);
    *(sv8*)(att + (size_t)s * 512 + lane * 8) = ov;
}

// ------------- LN(read) + LN(sence) + GeLU -------------
__global__ __launch_bounds__(256) void ln_gelu(const float* __restrict__ readb,
                                               const short* __restrict__ Y,
                                               const float* __restrict__ gamma,
                                               const float* __restrict__ beta,
                                               float* __restrict__ out) {
    int s = blockIdx.x;
    int tid = threadIdx.x;
    const float* r = readb + (size_t)s * 512;
    const short* sn = Y + (size_t)s * 2048 + 1536;
    float r0 = r[tid], r1 = r[tid + 256];
    float s0 = bf2f(sn[tid]), s1 = bf2f(sn[tid + 256]);

    float v0 = r0 + r1, v1 = r0 * r0 + r1 * r1;
    float v2 = s0 + s1, v3 = s0 * s0 + s1 * s1;
#pragma unroll
    for (int off = 32; off; off >>= 1) {
        v0 += __shfl_xor(v0, off);
        v1 += __shfl_xor(v1, off);
        v2 += __shfl_xor(v2, off);
        v3 += __shfl_xor(v3, off);
    }
    __shared__ float red[4][4];
    int wave = tid >> 6, lane = tid & 63;
    if (lane == 0) {
        red[wave][0] = v0; red[wave][1] = v1; red[wave][2] = v2; red[wave][3] = v3;
    }
    __syncthreads();
    float t0 = red[0][0] + red[1][0] + red[2][0] + red[3][0];
    float t1 = red[0][1] + red[1][1] + red[2][1] + red[3][1];
    float t2 = red[0][2] + red[1][2] + red[2][2] + red[3][2];
    float t3 = red[0][3] + red[1][3] + red[2][3] + red[3][3];

    float mu_r = t0 * (1.f / 512.f);
    float var_r = t1 * (1.f / 512.f) - mu_r * mu_r;
    float is_r = rsqrtf(var_r + 1e-5f);
    float mu_s = t2 * (1.f / 512.f);
    float var_s = t3 * (1.f / 512.f) - mu_s * mu_s;
    float is_s = rsqrtf(var_s + 1e-5f);

    float g0 = gamma[tid], be0 = beta[tid];
    float g1 = gamma[tid + 256], be1 = beta[tid + 256];
    float x0 = (r0 - mu_r) * is_r * g0 + be0 + (s0 - mu_s) * is_s * g0 + be0;
    float x1 = (r1 - mu_r) * is_r * g1 + be1 + (s1 - mu_s) * is_s * g1 + be1;
    float y0 = 0.5f * x0 * (1.f + erff(x0 * 0.70710678118654752f));
    float y1 = 0.5f * x1 * (1.f + erff(x1 * 0.70710678118654752f));
    out[(size_t)s * 512 + tid] = y0;
    out[(size_t)s * 512 + tid + 256] = y1;
}

extern "C" void kernel_launch(void* const* d_in, const int* in_sizes, int n_in,
                              void* d_out, int out_size, void* d_ws, size_t ws_size,
                              hipStream_t stream) {
    const float* x  = (const float*)d_in[0];
    const float* Wq = (const float*)d_in[1];
    const float* bq = (const float*)d_in[2];
    const float* Wk = (const float*)d_in[3];
    const float* bk = (const float*)d_in[4];
    const float* Wv = (const float*)d_in[5];
    const float* bv = (const float*)d_in[6];
    const float* Wo = (const float*)d_in[7];
    const float* bo = (const float*)d_in[8];
    const float* Wr = (const float*)d_in[9];
    const float* br = (const float*)d_in[10];
    const float* gamma = (const float*)d_in[11];
    const float* beta  = (const float*)d_in[12];

    char* ws = (char*)d_ws;
    short* xb   = (short*)(ws + OFF_XB);
    short* wt   = (short*)(ws + OFF_WT);
    float* ball = (float*)(ws + OFF_BIAS);
    short* Y    = (short*)(ws + OFF_Y);
    short* att  = (short*)(ws + OFF_ATT);
    float* readb = (float*)(ws + OFF_READ);

    cast_x<<<2048, 256, 0, stream>>>(x, xb, MTOT * DD / 4);
    cast_w<<<dim3(16, 16, 5), 256, 0, stream>>>(Wq, Wk, Wv, Wr, Wo, wt);
    prep_bias<<<8, 256, 0, stream>>>(bq, bk, bv, br, ball);

    // Y = [q|k|v|sence] : A=xb [4096][512], Bt=wt[0..3] stacked = [2048][512]
    gemm_bt<0><<<dim3(16, 32), 256, 0, stream>>>(xb, wt, ball, Y, 2048);

    attn_kernel<<<1024, 256, 0, stream>>>(Y, att);

    // read = att @ Wo + bo (fp32 out)
    gemm_bt<1><<<dim3(4, 32), 256, 0, stream>>>(att, wt + (size_t)4 * 512 * 512, bo,
                                                readb, 512);

    ln_gelu<<<4096, 256, 0, stream>>>(readb, Y, gamma, beta, (float*)d_out);
}

// Round 4
// 149.519 us; speedup vs baseline: 1.2372x; 1.2372x over previous
//
#include <hip/hip_runtime.h>
#include <hip/hip_bf16.h>
#include <math.h>

// Problem constants
#define BB 2
#define SS 2048
#define DD 512
#define MTOT 4096   // B*S
#define WINW 64

typedef __attribute__((ext_vector_type(8))) short sv8;   // 8 bf16
typedef __attribute__((ext_vector_type(4))) float f32x4;

// workspace layout (bytes)
static const size_t OFF_XB   = 0;               // bf16 x      [4096][512]   4 MB (dead after gemm1)
static const size_t OFF_WT   = 4194304;         // bf16 Wt     [5][512][512] 2.5 MB (q,k,v,r,o; [n][k])
static const size_t OFF_BIAS = 6815744;         // f32 bias    [2048]        8 KB (bq|bk|bv|br)
static const size_t OFF_Y    = 6823936;         // bf16 Y      [4096][2048]  16 MB (q|k|(unused v)|sence)
static const size_t OFF_VT   = 23601152;        // bf16 Vt     [2][512][2048] 4 MB (v transposed)
static const size_t OFF_PP   = 27795456;        // bf16 P'     [64][64][128]  1 MB (band probs, j-indexed)
static const size_t OFF_ATT  = 0;               // bf16 att    [4096][512]   4 MB (reuses XB)
static const size_t OFF_READ = 28844032;        // bf16 read   [4096][512]   4 MB

static __device__ __forceinline__ float bf2f(short s) {
    unsigned u = ((unsigned)(unsigned short)s) << 16;
    return __builtin_bit_cast(float, u);
}
static __device__ __forceinline__ short f2bf(float f) {
    unsigned u = __builtin_bit_cast(unsigned, f);
    unsigned r = 0x7fffu + ((u >> 16) & 1u);
    u += r;
    return (short)(u >> 16);
}

// ---------------- cast x to bf16 ----------------
__global__ __launch_bounds__(256) void cast_x(const float* __restrict__ x,
                                              short* __restrict__ xb, int n4) {
    int i = blockIdx.x * 256 + threadIdx.x;
    if (i < n4) {
        float4 v = ((const float4*)x)[i];
        short4 o;
        o.x = f2bf(v.x); o.y = f2bf(v.y); o.z = f2bf(v.z); o.w = f2bf(v.w);
        ((short4*)xb)[i] = o;
    }
}

// ------------- cast + transpose weights -> Wt[z][n][k] bf16 -------------
__global__ __launch_bounds__(256) void cast_w(const float* __restrict__ Wq,
                                              const float* __restrict__ Wk,
                                              const float* __restrict__ Wv,
                                              const float* __restrict__ Wr,
                                              const float* __restrict__ Wo,
                                              short* __restrict__ wt) {
    __shared__ float tile[32][33];
    int z = blockIdx.z;
    const float* W = (z == 0) ? Wq : (z == 1) ? Wk : (z == 2) ? Wv : (z == 3) ? Wr : Wo;
    int k0 = blockIdx.y * 32, n0 = blockIdx.x * 32;
    int tx = threadIdx.x & 31, ty = threadIdx.x >> 5;  // ty in 0..7
    for (int r = ty; r < 32; r += 8)
        tile[r][tx] = W[(size_t)(k0 + r) * 512 + n0 + tx];
    __syncthreads();
    short* o = wt + (size_t)z * 512 * 512;
    for (int r = ty; r < 32; r += 8)
        o[(size_t)(n0 + r) * 512 + k0 + tx] = f2bf(tile[tx][r]);
}

// ------------- concat biases -------------
__global__ __launch_bounds__(256) void prep_bias(const float* __restrict__ bq,
                                                 const float* __restrict__ bk,
                                                 const float* __restrict__ bv,
                                                 const float* __restrict__ br,
                                                 float* __restrict__ ball) {
    int i = blockIdx.x * 256 + threadIdx.x;  // 0..2047
    int sel = i >> 9;
    const float* src = (sel == 0) ? bq : (sel == 1) ? bk : (sel == 2) ? bv : br;
    ball[i] = src[i & 511];
}

// ------------- bf16 MFMA GEMM: C[m][n] = A[m][:] . Bt[n][:] + bias[n] -------------
// A: [M][512] bf16, Bt: [N][512] bf16, 128x128 tile, BK=64, bf16 out.
// If vt != null and this block's cols are the V segment [1024,1536), write
// transposed into vt[b][d][t] instead of Cout (packed short4: 4 consecutive t).
__global__ __launch_bounds__(256) void gemm_bt(const short* __restrict__ A,
                                               const short* __restrict__ Bt,
                                               const float* __restrict__ bias,
                                               short* __restrict__ Cout, int ldc,
                                               short* __restrict__ vt) {
    const int K = 512;
    const int LDL = 72;  // 64 + 8 pad
    __shared__ __align__(16) short lA[128 * LDL];
    __shared__ __align__(16) short lB[128 * LDL];
    int tid = threadIdx.x;
    int mbase = blockIdx.y * 128;
    int nbase = blockIdx.x * 128;
    int lane = tid & 63, wave = tid >> 6;
    int wm = wave >> 1, wn = wave & 1;

    f32x4 acc[4][4] = {};

    for (int k0 = 0; k0 < K; k0 += 64) {
#pragma unroll
        for (int t = 0; t < 4; ++t) {
            int c = tid + t * 256;           // 0..1023
            int row = c >> 3, slot = c & 7;  // 128 rows x 8 x 16B
            sv8 va = *(const sv8*)(A + (size_t)(mbase + row) * K + k0 + slot * 8);
            *(sv8*)&lA[row * LDL + slot * 8] = va;
            sv8 vb = *(const sv8*)(Bt + (size_t)(nbase + row) * K + k0 + slot * 8);
            *(sv8*)&lB[row * LDL + slot * 8] = vb;
        }
        __syncthreads();
#pragma unroll
        for (int kk = 0; kk < 2; ++kk) {
            int koff = kk * 32 + (lane >> 4) * 8;
            sv8 af[4], bfr[4];
#pragma unroll
            for (int m = 0; m < 4; ++m)
                af[m] = *(const sv8*)&lA[(wm * 64 + m * 16 + (lane & 15)) * LDL + koff];
#pragma unroll
            for (int n = 0; n < 4; ++n)
                bfr[n] = *(const sv8*)&lB[(wn * 64 + n * 16 + (lane & 15)) * LDL + koff];
#pragma unroll
            for (int m = 0; m < 4; ++m)
#pragma unroll
                for (int n = 0; n < 4; ++n)
                    acc[m][n] = __builtin_amdgcn_mfma_f32_16x16x32_bf16(
                        af[m], bfr[n], acc[m][n], 0, 0, 0);
        }
        __syncthreads();
    }

    // epilogue: D[row=(lane>>4)*4+j][col=lane&15] per 16x16 fragment
    int r0 = (lane >> 4) * 4, c0 = lane & 15;
    bool tovt = (vt != nullptr) && (nbase >= 1024) && (nbase < 1536);
#pragma unroll
    for (int m = 0; m < 4; ++m) {
#pragma unroll
        for (int n = 0; n < 4; ++n) {
            int col = nbase + wn * 64 + n * 16 + c0;
            float bv = bias[col];
            if (tovt) {
                int d = col - 1024;
                int row0 = mbase + wm * 64 + m * 16 + r0;
                int bb = row0 >> 11, t = row0 & 2047;
                short4 o;
                o.x = f2bf(acc[m][n][0] + bv);
                o.y = f2bf(acc[m][n][1] + bv);
                o.z = f2bf(acc[m][n][2] + bv);
                o.w = f2bf(acc[m][n][3] + bv);
                *(short4*)(vt + (size_t)(bb * 512 + d) * 2048 + t) = o;
            } else {
#pragma unroll
                for (int j = 0; j < 4; ++j) {
                    int row = mbase + wm * 64 + m * 16 + r0 + j;
                    Cout[(size_t)row * ldc + col] = f2bf(acc[m][n][j] + bv);
                }
            }
        }
    }
}

// ------------- attention scores + softmax -> band probs P' -------------
// q-tile of 64 queries (s0..s0+63), key window of 128: kr = t0-64+j, j=0..127.
// Valid band: j in [i+1, i+64] and kr >= 0 (i = query offset in tile).
// P'[tile][i][j] bf16, zero outside band.
__global__ __launch_bounds__(256) void attn_scores(const short* __restrict__ Y,
                                                   short* __restrict__ Pp) {
    __shared__ float sS[64][132];
    int tile = blockIdx.x;  // 0..63
    int b = tile >> 5;
    int t0 = (tile & 31) * 64;
    int s0 = tile * 64;
    int tid = threadIdx.x, lane = tid & 63, wave = tid >> 6;
    int wm = wave >> 1, wn = wave & 1;

    f32x4 acc[2][4] = {};
    const short* Q = Y;
    const short* Kb = Y + 512;

    int arow[2], brow[4];
#pragma unroll
    for (int m = 0; m < 2; ++m) arow[m] = s0 + wm * 32 + m * 16 + (lane & 15);
#pragma unroll
    for (int n = 0; n < 4; ++n) {
        int kr = t0 - 64 + wn * 64 + n * 16 + (lane & 15);
        if (kr < 0) kr = 0;  // masked later
        brow[n] = (b << 11) + kr;
    }
#pragma unroll
    for (int step = 0; step < 16; ++step) {
        int koff = step * 32 + (lane >> 4) * 8;
        sv8 af[2], bfr[4];
#pragma unroll
        for (int m = 0; m < 2; ++m)
            af[m] = *(const sv8*)(Q + (size_t)arow[m] * 2048 + koff);
#pragma unroll
        for (int n = 0; n < 4; ++n)
            bfr[n] = *(const sv8*)(Kb + (size_t)brow[n] * 2048 + koff);
#pragma unroll
        for (int m = 0; m < 2; ++m)
#pragma unroll
            for (int n = 0; n < 4; ++n)
                acc[m][n] = __builtin_amdgcn_mfma_f32_16x16x32_bf16(
                    af[m], bfr[n], acc[m][n], 0, 0, 0);
    }
    int r0 = (lane >> 4) * 4, c0 = lane & 15;
#pragma unroll
    for (int m = 0; m < 2; ++m)
#pragma unroll
        for (int n = 0; n < 4; ++n) {
            int jc = wn * 64 + n * 16 + c0;
#pragma unroll
            for (int j = 0; j < 4; ++j)
                sS[wm * 32 + m * 16 + r0 + j][jc] =
                    acc[m][n][j] * 0.04419417382415922f;  // 1/sqrt(512)
        }
    __syncthreads();

    // softmax: thread -> (q = tid>>2, quarter = tid&3), 4 lanes per row (same wave)
    int q = tid >> 2, j0 = (tid & 3) * 32;
    float v[32];
    float mx = -1e30f;
    int jlo = q + 1;
    int jmin0 = 64 - t0;
    if (jmin0 > jlo) jlo = jmin0;
    int jhi = q + 64;
#pragma unroll
    for (int jj = 0; jj < 32; ++jj) {
        int j = j0 + jj;
        bool ok = (j >= jlo) && (j <= jhi);
        float s = ok ? sS[q][j] : -1e30f;
        v[jj] = s;
        mx = fmaxf(mx, s);
    }
    mx = fmaxf(mx, __shfl_xor(mx, 1));
    mx = fmaxf(mx, __shfl_xor(mx, 2));
    float sum = 0.f;
#pragma unroll
    for (int jj = 0; jj < 32; ++jj) {
        float e = (v[jj] > -1e29f) ? __expf(v[jj] - mx) : 0.f;
        v[jj] = e;
        sum += e;
    }
    sum += __shfl_xor(sum, 1);
    sum += __shfl_xor(sum, 2);
    float inv = 1.f / sum;
    short* dst = Pp + (size_t)tile * 8192 + q * 128 + j0;
#pragma unroll
    for (int k = 0; k < 4; ++k) {
        sv8 o;
#pragma unroll
        for (int e = 0; e < 8; ++e) o[e] = f2bf(v[k * 8 + e] * inv);
        *(sv8*)(dst + k * 8) = o;
    }
}

// ------------- PV: att[64 x 512-chunk] = P'[64x128] @ V[128 x d] via Vt -------------
__global__ __launch_bounds__(256) void attn_pv(const short* __restrict__ Pp,
                                               const short* __restrict__ Vt,
                                               short* __restrict__ att) {
    int tile = blockIdx.y, dchunk = blockIdx.x;  // 64 tiles x 4 d-chunks of 128
    int b = tile >> 5;
    int t0 = (tile & 31) * 64;
    int s0 = tile * 64;
    int tid = threadIdx.x, lane = tid & 63, wave = tid >> 6;
    int wm = wave >> 1, wn = wave & 1;

    f32x4 acc[2][4] = {};
    const short* Pbase = Pp + (size_t)tile * 8192;
#pragma unroll
    for (int ks = 0; ks < 4; ++ks) {
        int koff = ks * 32 + (lane >> 4) * 8;
        sv8 af[2], bfr[4];
#pragma unroll
        for (int m = 0; m < 2; ++m)
            af[m] = *(const sv8*)(Pbase + (wm * 32 + m * 16 + (lane & 15)) * 128 + koff);
#pragma unroll
        for (int n = 0; n < 4; ++n) {
            int d = dchunk * 128 + wn * 64 + n * 16 + (lane & 15);
            long off = (long)(b * 512 + d) * 2048 + (t0 - 64 + koff);  // may be -64 at t0=0 (p=0 there)
            bfr[n] = *(const sv8*)(Vt + off);
        }
#pragma unroll
        for (int m = 0; m < 2; ++m)
#pragma unroll
            for (int n = 0; n < 4; ++n)
                acc[m][n] = __builtin_amdgcn_mfma_f32_16x16x32_bf16(
                    af[m], bfr[n], acc[m][n], 0, 0, 0);
    }
    int r0 = (lane >> 4) * 4, c0 = lane & 15;
#pragma unroll
    for (int m = 0; m < 2; ++m)
#pragma unroll
        for (int n = 0; n < 4; ++n) {
            int col = dchunk * 128 + wn * 64 + n * 16 + c0;
#pragma unroll
            for (int j = 0; j < 4; ++j) {
                int row = s0 + wm * 32 + m * 16 + r0 + j;
                att[(size_t)row * 512 + col] = f2bf(acc[m][n][j]);
            }
        }
}

// ------------- LN(read) + LN(sence) + GeLU -------------
__global__ __launch_bounds__(256) void ln_gelu(const short* __restrict__ readb,
                                               const short* __restrict__ Y,
                                               const float* __restrict__ gamma,
                                               const float* __restrict__ beta,
                                               float* __restrict__ out) {
    int s = blockIdx.x;
    int tid = threadIdx.x;
    const short* r = readb + (size_t)s * 512;
    const short* sn = Y + (size_t)s * 2048 + 1536;
    float r0 = bf2f(r[tid]), r1 = bf2f(r[tid + 256]);
    float s0 = bf2f(sn[tid]), s1 = bf2f(sn[tid + 256]);

    float v0 = r0 + r1, v1 = r0 * r0 + r1 * r1;
    float v2 = s0 + s1, v3 = s0 * s0 + s1 * s1;
#pragma unroll
    for (int off = 32; off; off >>= 1) {
        v0 += __shfl_xor(v0, off);
        v1 += __shfl_xor(v1, off);
        v2 += __shfl_xor(v2, off);
        v3 += __shfl_xor(v3, off);
    }
    __shared__ float red[4][4];
    int wave = tid >> 6, lane = tid & 63;
    if (lane == 0) {
        red[wave][0] = v0; red[wave][1] = v1; red[wave][2] = v2; red[wave][3] = v3;
    }
    __syncthreads();
    float t0 = red[0][0] + red[1][0] + red[2][0] + red[3][0];
    float t1 = red[0][1] + red[1][1] + red[2][1] + red[3][1];
    float t2 = red[0][2] + red[1][2] + red[2][2] + red[3][2];
    float t3 = red[0][3] + red[1][3] + red[2][3] + red[3][3];

    float mu_r = t0 * (1.f / 512.f);
    float var_r = t1 * (1.f / 512.f) - mu_r * mu_r;
    float is_r = rsqrtf(var_r + 1e-5f);
    float mu_s = t2 * (1.f / 512.f);
    float var_s = t3 * (1.f / 512.f) - mu_s * mu_s;
    float is_s = rsqrtf(var_s + 1e-5f);

    float g0 = gamma[tid], be0 = beta[tid];
    float g1 = gamma[tid + 256], be1 = beta[tid + 256];
    float x0 = (r0 - mu_r) * is_r * g0 + be0 + (s0 - mu_s) * is_s * g0 + be0;
    float x1 = (r1 - mu_r) * is_r * g1 + be1 + (s1 - mu_s) * is_s * g1 + be1;
    float y0 = 0.5f * x0 * (1.f + erff(x0 * 0.70710678118654752f));
    float y1 = 0.5f * x1 * (1.f + erff(x1 * 0.70710678118654752f));
    out[(size_t)s * 512 + tid] = y0;
    out[(size_t)s * 512 + tid + 256] = y1;
}

extern "C" void kernel_launch(void* const* d_in, const int* in_sizes, int n_in,
                              void* d_out, int out_size, void* d_ws, size_t ws_size,
                              hipStream_t stream) {
    const float* x  = (const float*)d_in[0];
    const float* Wq = (const float*)d_in[1];
    const float* bq = (const float*)d_in[2];
    const float* Wk = (const float*)d_in[3];
    const float* bk = (const float*)d_in[4];
    const float* Wv = (const float*)d_in[5];
    const float* bv = (const float*)d_in[6];
    const float* Wo = (const float*)d_in[7];
    const float* bo = (const float*)d_in[8];
    const float* Wr = (const float*)d_in[9];
    const float* br = (const float*)d_in[10];
    const float* gamma = (const float*)d_in[11];
    const float* beta  = (const float*)d_in[12];

    char* ws = (char*)d_ws;
    short* xb    = (short*)(ws + OFF_XB);
    short* wt    = (short*)(ws + OFF_WT);
    float* ball  = (float*)(ws + OFF_BIAS);
    short* Y     = (short*)(ws + OFF_Y);
    short* vtb   = (short*)(ws + OFF_VT);
    short* Pp    = (short*)(ws + OFF_PP);
    short* att   = (short*)(ws + OFF_ATT);   // overlays xb (dead after gemm1)
    short* readb = (short*)(ws + OFF_READ);

    cast_x<<<2048, 256, 0, stream>>>(x, xb, MTOT * DD / 4);
    cast_w<<<dim3(16, 16, 5), 256, 0, stream>>>(Wq, Wk, Wv, Wr, Wo, wt);
    prep_bias<<<8, 256, 0, stream>>>(bq, bk, bv, br, ball);

    // Y = [q|k|v|sence]; v segment routed transposed into vtb
    gemm_bt<<<dim3(16, 32), 256, 0, stream>>>(xb, wt, ball, Y, 2048, vtb);

    attn_scores<<<64, 256, 0, stream>>>(Y, Pp);
    attn_pv<<<dim3(4, 64), 256, 0, stream>>>(Pp, vtb, att);

    // read = att @ Wo + bo (bf16 out)
    gemm_bt<<<dim3(4, 32), 256, 0, stream>>>(att, wt + (size_t)4 * 512 * 512, bo,
                                             readb, 512, nullptr);

    ln_gelu<<<4096, 256, 0, stream>>>(readb, Y, gamma, beta, (float*)d_out);
}